// Round 1
// baseline (4164.951 us; speedup 1.0000x reference)
//
#include <hip/hip_runtime.h>
#include <math.h>

// Problem constants
#define BB 64
#define SS 80
#define TT 20
#define FF 4096
#define HH 256
#define VV 32000

__device__ __forceinline__ float fsig(float x){ return 1.f/(1.f+__expf(-x)); }
__device__ __forceinline__ float ftanh(float x){
    float xc = fminf(fmaxf(x,-15.f),15.f);
    float e = __expf(2.f*xc);
    return (e-1.f)/(e+1.f);
}

// ---------------------------------------------------------------------------
// prep: weight transposes, M3 = att_Wc @ cov_k, bias sums, gather indices
// ---------------------------------------------------------------------------
__global__ __launch_bounds__(256) void prep_kernel(
    const float* __restrict__ eWhh0, const float* __restrict__ eWih1, const float* __restrict__ eWhh1,
    const float* __restrict__ dWih0, const float* __restrict__ dWhh0, const float* __restrict__ dWih1,
    const float* __restrict__ dWhh1, const float* __restrict__ attWs, const float* __restrict__ attWc,
    const float* __restrict__ cov_w, const float* __restrict__ cov_b,
    const float* __restrict__ e_bih0, const float* __restrict__ e_bhh0,
    const float* __restrict__ e_bih1, const float* __restrict__ e_bhh1,
    const float* __restrict__ d_bih0, const float* __restrict__ d_bhh0,
    const float* __restrict__ d_bih1, const float* __restrict__ d_bhh1,
    const int*   __restrict__ captions,
    float* WhhT0e, float* WihT1e, float* WhhT1e, float* dWih0T, float* dWhh0T,
    float* dWih1T, float* dWhh1T, float* aWsT, float* M3, float* attcb,
    float* b0e, float* b1e, float* b0d, float* b1d, int* g2, int* g3)
{
    int blk = blockIdx.x, tid = threadIdx.x;
    const float* src = nullptr; float* dst = nullptr; int R=0, C=0, t0=0;
    if      (blk < 256)  { src=eWhh0; dst=WhhT0e; R=1024; C=256; t0=0; }
    else if (blk < 512)  { src=eWih1; dst=WihT1e; R=1024; C=256; t0=256; }
    else if (blk < 768)  { src=eWhh1; dst=WhhT1e; R=1024; C=256; t0=512; }
    else if (blk < 1280) { src=dWih0; dst=dWih0T; R=1024; C=512; t0=768; }
    else if (blk < 1536) { src=dWhh0; dst=dWhh0T; R=1024; C=256; t0=1280; }
    else if (blk < 1792) { src=dWih1; dst=dWih1T; R=1024; C=256; t0=1536; }
    else if (blk < 2048) { src=dWhh1; dst=dWhh1T; R=1024; C=256; t0=1792; }
    else if (blk < 2112) { src=attWs; dst=aWsT;   R=256;  C=256; t0=2048; }
    else if (blk == 2112) {
        // M3[h][k] = sum_c att_Wc[h][c]*cov_w[c][0][k];  attcb[h] = att_Wc[h]·cov_b
        float m0=0.f,m1=0.f,m2=0.f,cb=0.f;
        for (int c=0;c<64;c++){
            float w = attWc[tid*64+c];
            m0 += w*cov_w[c*3+0]; m1 += w*cov_w[c*3+1]; m2 += w*cov_w[c*3+2];
            cb += w*cov_b[c];
        }
        M3[tid*3+0]=m0; M3[tid*3+1]=m1; M3[tid*3+2]=m2; attcb[tid]=cb;
        return;
    } else if (blk == 2113) {
        for (int i=tid;i<1024;i+=256){
            b0e[i]=e_bih0[i]+e_bhh0[i]; b1e[i]=e_bih1[i]+e_bhh1[i];
            b0d[i]=d_bih0[i]+d_bhh0[i]; b1d[i]=d_bih1[i]+d_bhh1[i];
        }
        return;
    } else if (blk == 2114) {
        for (int m=tid;m<SS*BB;m+=256) g2[m] = (m&63)*SS + (m>>6); // A-row = b*80+t for C-row t*64+b
        return;
    } else {
        for (int m=tid;m<TT*BB;m+=256) g3[m] = captions[(m&63)*TT + (m>>6)];
        return;
    }
    // 32x32 tile transpose
    int tl = blk - t0; int ctn = C/32; int rt = tl/ctn, ct = tl%ctn;
    __shared__ float tile[32][33];
    int ty = tid>>5, tx = tid&31;
    #pragma unroll
    for (int i=0;i<4;i++){ int r=ty+i*8; tile[r][tx] = src[(size_t)(rt*32+r)*C + ct*32+tx]; }
    __syncthreads();
    #pragma unroll
    for (int i=0;i<4;i++){ int r=ty+i*8; dst[(size_t)(ct*32+r)*R + rt*32+tx] = tile[tx][r]; }
}

// ---------------------------------------------------------------------------
// Generic tiled fp32 GEMM: C[M,N] = A[M,K] @ B[N,K]^T (+bias), optional A-row gather
// ---------------------------------------------------------------------------
template<int BM,int BN,int TM,int TN>
__global__ __launch_bounds__(256) void gemm_nt(int M,int N,int K,
    const float* __restrict__ A, int lda,
    const float* __restrict__ B, int ldb,
    float* __restrict__ C, int ldc,
    const float* __restrict__ bias,
    const int* __restrict__ gatherA)
{
    constexpr int BK=16;
    constexpr int TX=BN/TN, TY=BM/TM;
    static_assert(TX*TY==256, "256 threads");
    __shared__ float As[BK][BM+4];
    __shared__ float Bs[BK][BN+4];
    int tid = threadIdx.x;
    int tx = tid%TX, ty = tid/TX;
    int m0 = blockIdx.y*BM, n0 = blockIdx.x*BN;
    float acc[TM][TN] = {};
    int lr = tid>>2, lk = (tid&3)*4;
    for (int k0=0;k0<K;k0+=BK){
        #pragma unroll
        for (int r=lr;r<BM;r+=64){
            int arow = gatherA ? gatherA[m0+r] : (m0+r);
            float4 v = *reinterpret_cast<const float4*>(A + (size_t)arow*lda + k0 + lk);
            As[lk+0][r]=v.x; As[lk+1][r]=v.y; As[lk+2][r]=v.z; As[lk+3][r]=v.w;
        }
        #pragma unroll
        for (int r=lr;r<BN;r+=64){
            float4 v = *reinterpret_cast<const float4*>(B + (size_t)(n0+r)*ldb + k0 + lk);
            Bs[lk+0][r]=v.x; Bs[lk+1][r]=v.y; Bs[lk+2][r]=v.z; Bs[lk+3][r]=v.w;
        }
        __syncthreads();
        #pragma unroll
        for (int k=0;k<BK;k++){
            float a[TM], bv[TN];
            #pragma unroll
            for (int i=0;i<TM;i++) a[i]=As[k][ty*TM+i];
            #pragma unroll
            for (int j=0;j<TN;j++) bv[j]=Bs[k][tx*TN+j];
            #pragma unroll
            for (int i=0;i<TM;i++)
                #pragma unroll
                for (int j=0;j<TN;j++) acc[i][j] += a[i]*bv[j];
        }
        __syncthreads();
    }
    #pragma unroll
    for (int i=0;i<TM;i++){
        size_t m = m0 + ty*TM + i;
        #pragma unroll
        for (int j=0;j<TN;j++){
            int n = n0 + tx*TN + j;
            C[m*ldc + n] = acc[i][j] + (bias ? bias[n] : 0.f);
        }
    }
}

// ---------------------------------------------------------------------------
// LSTM z + pointwise for a 4-batch x 32-h block (128 blocks cover 64b x 256h)
// z = base + x@WxT + h@WhT (+bias);  i,f,g,o gates -> c,h update
// ---------------------------------------------------------------------------
__device__ __forceinline__ void lstm_body(int lb, int tid,
    const float* __restrict__ xrow, const float* __restrict__ hrow,
    const float* __restrict__ WxT, const float* __restrict__ WhT,
    const float* __restrict__ bias, const float* __restrict__ baserows,
    float* __restrict__ cbuf, float* __restrict__ hout,
    float* __restrict__ extra, int extra_stride)
{
    int bc = lb>>3, hc = lb&7, b0 = bc*4;
    __shared__ float xs[4][256];
    __shared__ float hs[4][256];
    __shared__ float zs[4][4][32];
    for (int i=tid;i<1024;i+=256){
        int bb2=i>>8, k=i&255;
        hs[bb2][k] = hrow[(b0+bb2)*256 + k];
        if (xrow) xs[bb2][k] = xrow[(b0+bb2)*256 + k];
    }
    __syncthreads();
    int b_l = tid>>6, inner = tid&63, gate = inner>>5, h_l = inner&31;
    int b = b0 + b_l;
    int j0 = gate*256 + hc*32 + h_l;   // gates 0,1 ; +512 -> gates 2,3
    float acc0 = 0.f, acc1 = 0.f;
    if (bias)     { acc0 += bias[j0];                       acc1 += bias[j0+512]; }
    if (baserows) { acc0 += baserows[(size_t)b*1024 + j0];  acc1 += baserows[(size_t)b*1024 + j0 + 512]; }
    const float* wh = WhT + j0;
    if (WxT){
        const float* wx = WxT + j0;
        #pragma unroll 2
        for (int k=0;k<256;k++){
            float xv = xs[b_l][k], hv = hs[b_l][k];
            acc0 += xv*wx[(size_t)k*1024]     + hv*wh[(size_t)k*1024];
            acc1 += xv*wx[(size_t)k*1024+512] + hv*wh[(size_t)k*1024+512];
        }
    } else {
        #pragma unroll 4
        for (int k=0;k<256;k++){
            float hv = hs[b_l][k];
            acc0 += hv*wh[(size_t)k*1024];
            acc1 += hv*wh[(size_t)k*1024+512];
        }
    }
    zs[b_l][gate  ][h_l] = acc0;
    zs[b_l][gate+2][h_l] = acc1;
    __syncthreads();
    if (tid < 128){
        int pb = tid>>5, ph = tid&31;
        int bb2 = b0+pb, h = hc*32+ph, idx = bb2*256 + h;
        float i_ = zs[pb][0][ph], f_ = zs[pb][1][ph], g_ = zs[pb][2][ph], o_ = zs[pb][3][ph];
        float cn = fsig(f_)*cbuf[idx] + fsig(i_)*ftanh(g_);
        cbuf[idx] = cn;
        float hn = fsig(o_)*ftanh(cn);
        hout[idx] = hn;
        if (extra) extra[(size_t)bb2*extra_stride + h] = hn;
    }
}

// Encoder: pipelined — blocks 0..127 do layer0 step t, blocks 128..255 do layer1 step t-1
__global__ __launch_bounds__(256) void enc_step(int t,
    const float* __restrict__ zx0, const float* __restrict__ WhhT0e,
    const float* __restrict__ WihT1e, const float* __restrict__ WhhT1e,
    const float* __restrict__ b1e,
    float* h1buf, float* c1, float* h2buf, float* c2, float* enc_out)
{
    int blk = blockIdx.x, tid = threadIdx.x;
    if (blk < 128){
        if (t >= SS) return;
        const float* h1prev = h1buf + ((t+1)&1)*16384;
        float* h1cur        = h1buf + (t&1)*16384;
        lstm_body(blk, tid, nullptr, h1prev, nullptr, WhhT0e, nullptr,
                  zx0 + (size_t)t*65536, c1, h1cur, nullptr, 0);
    } else {
        if (t < 1) return;
        int u = t-1;
        const float* h1row  = h1buf + (u&1)*16384;
        const float* h2prev = h2buf + (u&1)*16384;
        float* h2next       = h2buf + ((u+1)&1)*16384;
        lstm_body(blk-128, tid, h1row, h2prev, WihT1e, WhhT1e, b1e, nullptr,
                  c2, h2next, enc_out + (size_t)u*256, SS*256);
    }
}

// Decoder LSTM half-step (grid 128)
__global__ __launch_bounds__(256) void dec_lstm(
    const float* __restrict__ xrow, const float* __restrict__ hrow,
    const float* __restrict__ WxT, const float* __restrict__ WhT,
    const float* __restrict__ bias, const float* __restrict__ baserows,
    float* cbuf, float* hout)
{
    lstm_body(blockIdx.x, threadIdx.x, xrow, hrow, WxT, WhT, bias, baserows,
              cbuf, hout, nullptr, 0);
}

// ---------------------------------------------------------------------------
// Decoder attention (one block per batch row)
// ---------------------------------------------------------------------------
__global__ __launch_bounds__(256) void dec_attn(
    const float* __restrict__ h2prev, const float* __restrict__ encp,
    const float* __restrict__ enco, const float* __restrict__ WsT,
    const float* __restrict__ att_v, const float* __restrict__ M3,
    const float* __restrict__ attcb, float* __restrict__ cov,
    float* __restrict__ ctx)
{
    int b = blockIdx.x, tid = threadIdx.x;
    __shared__ float h2s[256], dps[256];
    __shared__ float covs[82], scs[80], attns[80];
    h2s[tid] = h2prev[b*256 + tid];
    if (tid < 80) covs[tid+1] = cov[b*80 + tid];
    if (tid == 80) covs[0] = 0.f;
    if (tid == 81) covs[81] = 0.f;
    __syncthreads();
    // dec_proj[h] + attcb[h]
    {
        float acc = attcb[tid];
        for (int k=0;k<256;k++) acc += h2s[k]*WsT[k*256 + tid];
        dps[tid] = acc;
    }
    __syncthreads();
    // scores: wave w handles s in [w*20, w*20+20)
    int wave = tid>>6, lane = tid&63;
    float va[4], dp4[4], m30[4], m31[4], m32[4];
    #pragma unroll
    for (int i=0;i<4;i++){
        int h = lane + i*64;
        va[i]=att_v[h]; dp4[i]=dps[h];
        m30[i]=M3[h*3+0]; m31[i]=M3[h*3+1]; m32[i]=M3[h*3+2];
    }
    for (int s = wave*20; s < wave*20 + 20; s++){
        float c0 = covs[s], c1v = covs[s+1], c2v = covs[s+2];
        float p = 0.f;
        #pragma unroll
        for (int i=0;i<4;i++){
            int h = lane + i*64;
            float e = encp[((size_t)b*80 + s)*256 + h] + dp4[i] + m30[i]*c0 + m31[i]*c1v + m32[i]*c2v;
            p += va[i]*ftanh(e);
        }
        #pragma unroll
        for (int off=32;off;off>>=1) p += __shfl_down(p, off);
        if (lane == 0) scs[s] = p;
    }
    __syncthreads();
    // softmax over 80 (wave 0)
    if (tid < 64){
        float a = scs[tid];
        float bsc = (tid < 16) ? scs[tid+64] : -3.4e38f;
        float mx = fmaxf(a, bsc);
        #pragma unroll
        for (int off=32;off;off>>=1) mx = fmaxf(mx, __shfl_xor(mx, off));
        float ea = __expf(a - mx);
        float eb = (tid < 16) ? __expf(bsc - mx) : 0.f;
        float sum = ea + eb;
        #pragma unroll
        for (int off=32;off;off>>=1) sum += __shfl_xor(sum, off);
        float inv = 1.f/sum;
        attns[tid] = ea*inv;
        if (tid < 16) attns[tid+64] = eb*inv;
    }
    __syncthreads();
    if (tid < 80) cov[b*80 + tid] = covs[tid+1] + attns[tid];
    // ctx
    float cacc = 0.f;
    for (int s=0;s<80;s++) cacc += attns[s]*enco[((size_t)b*80 + s)*256 + tid];
    ctx[b*256 + tid] = cacc;
}

// ---------------------------------------------------------------------------
// LayerNorm rows of h2_all[t][b] -> normed[b*20+t]
// ---------------------------------------------------------------------------
__global__ __launch_bounds__(256) void ln_kernel(
    const float* __restrict__ h2all, const float* __restrict__ g,
    const float* __restrict__ be, float* __restrict__ normed)
{
    int row = blockIdx.x;           // b*20 + t
    int b = row/TT, t = row%TT;
    int tid = threadIdx.x;
    __shared__ float red[4];
    float x = h2all[((size_t)t*64 + b)*256 + tid];
    float s = x;
    #pragma unroll
    for (int off=32;off;off>>=1) s += __shfl_down(s, off);
    if ((tid&63) == 0) red[tid>>6] = s;
    __syncthreads();
    float mean = (red[0]+red[1]+red[2]+red[3]) * (1.f/256.f);
    __syncthreads();
    float d = x - mean;
    float sq = d*d;
    #pragma unroll
    for (int off=32;off;off>>=1) sq += __shfl_down(sq, off);
    if ((tid&63) == 0) red[tid>>6] = sq;
    __syncthreads();
    float var = (red[0]+red[1]+red[2]+red[3]) * (1.f/256.f);
    normed[(size_t)row*256 + tid] = d*rsqrtf(var + 1e-5f)*g[tid] + be[tid];
}

// ---------------------------------------------------------------------------
extern "C" void kernel_launch(void* const* d_in, const int* in_sizes, int n_in,
                              void* d_out, int out_size, void* d_ws, size_t ws_size,
                              hipStream_t stream)
{
    const float* video  = (const float*)d_in[0];
    const int*   caps   = (const int*)  d_in[1];
    const float* W_vp   = (const float*)d_in[2];
    const float* b_vp   = (const float*)d_in[3];
    const float* eWih0  = (const float*)d_in[4];
    const float* eWhh0  = (const float*)d_in[5];
    const float* e_bih0 = (const float*)d_in[6];
    const float* e_bhh0 = (const float*)d_in[7];
    const float* eWih1  = (const float*)d_in[8];
    const float* eWhh1  = (const float*)d_in[9];
    const float* e_bih1 = (const float*)d_in[10];
    const float* e_bhh1 = (const float*)d_in[11];
    const float* emb    = (const float*)d_in[12];
    const float* dWih0  = (const float*)d_in[13];
    const float* dWhh0  = (const float*)d_in[14];
    const float* d_bih0 = (const float*)d_in[15];
    const float* d_bhh0 = (const float*)d_in[16];
    const float* dWih1  = (const float*)d_in[17];
    const float* dWhh1  = (const float*)d_in[18];
    const float* d_bih1 = (const float*)d_in[19];
    const float* d_bhh1 = (const float*)d_in[20];
    const float* attWh  = (const float*)d_in[21];
    const float* attWs  = (const float*)d_in[22];
    const float* att_v  = (const float*)d_in[23];
    const float* attWc  = (const float*)d_in[24];
    const float* cov_w  = (const float*)d_in[25];
    const float* cov_b  = (const float*)d_in[26];
    const float* ln_g   = (const float*)d_in[27];
    const float* ln_b   = (const float*)d_in[28];
    const float* W_out  = (const float*)d_in[29];
    const float* b_out  = (const float*)d_in[30];
    float* out = (float*)d_out;

    float* W = (float*)d_ws;
    size_t o = 0;
    auto alloc = [&](size_t n){ size_t r = o; o += ((n + 63)/64)*64; return r; };

    // zero-initialized state region (contiguous, memset below)
    float* h1buf = W + alloc(2*64*256);
    float* h2buf = W + alloc(2*64*256);
    float* c1    = W + alloc(64*256);
    float* c2    = W + alloc(64*256);
    float* cov   = W + alloc(64*80);
    size_t state_bytes = o * sizeof(float);

    float* h1dec   = W + alloc(2*64*256);
    float* vp      = W + alloc((size_t)SS*BB*HH);       // [b][s][h]
    float* zx0     = W + alloc((size_t)SS*BB*1024);     // [t][b][1024]
    float* embproj = W + alloc((size_t)TT*BB*1024);     // [t][b][1024]
    float* enc_out = W + alloc((size_t)BB*SS*HH);       // [b][s][h]
    float* encproj = W + alloc((size_t)BB*SS*HH);       // [b][s][h]
    float* h2all   = W + alloc((size_t)TT*BB*HH);       // [t][b][h]
    float* ctx     = W + alloc((size_t)BB*HH);
    float* normed  = W + alloc((size_t)BB*TT*HH);       // [b*20+t][h]
    float* WhhT0e  = W + alloc(256*1024);
    float* WihT1e  = W + alloc(256*1024);
    float* WhhT1e  = W + alloc(256*1024);
    float* dWih0T  = W + alloc(512*1024);
    float* dWhh0T  = W + alloc(256*1024);
    float* dWih1T  = W + alloc(256*1024);
    float* dWhh1T  = W + alloc(256*1024);
    float* aWsT    = W + alloc(256*256);
    float* M3      = W + alloc(256*3);
    float* attcb   = W + alloc(256);
    float* b0e     = W + alloc(1024);
    float* b1e     = W + alloc(1024);
    float* b0d     = W + alloc(1024);
    float* b1d     = W + alloc(1024);
    int*   g2      = (int*)(W + alloc(SS*BB));
    int*   g3      = (int*)(W + alloc(TT*BB));
    (void)ws_size; (void)n_in; (void)in_sizes; (void)out_size;

    hipMemsetAsync(W, 0, state_bytes, stream);

    prep_kernel<<<2116, 256, 0, stream>>>(
        eWhh0, eWih1, eWhh1, dWih0, dWhh0, dWih1, dWhh1, attWs, attWc,
        cov_w, cov_b, e_bih0, e_bhh0, e_bih1, e_bhh1, d_bih0, d_bhh0, d_bih1, d_bhh1,
        caps, WhhT0e, WihT1e, WhhT1e, dWih0T, dWhh0T, dWih1T, dWhh1T, aWsT,
        M3, attcb, b0e, b1e, b0d, b1d, g2, g3);

    // vp = video @ W_vp^T + b_vp          (5120 x 256, K=4096)
    gemm_nt<64,128,4,8><<<dim3(2,80), 256, 0, stream>>>(
        SS*BB, HH, FF, video, FF, W_vp, FF, vp, HH, b_vp, nullptr);

    // zx0[t][b] = vp[b][t] @ eWih0^T + (bih0+bhh0)    (5120 x 1024, K=256)
    gemm_nt<64,64,4,4><<<dim3(16,80), 256, 0, stream>>>(
        SS*BB, 1024, HH, vp, HH, eWih0, HH, zx0, 1024, b0e, g2);

    // embproj[t][b] = emb[tok] @ dWih0[:, :256]^T + (bih0+bhh0)   (1280 x 1024, K=256)
    gemm_nt<64,64,4,4><<<dim3(16,20), 256, 0, stream>>>(
        TT*BB, 1024, HH, emb, HH, dWih0, 512, embproj, 1024, b0d, g3);

    // encoder scan (pipelined: layer0(t) || layer1(t-1))
    for (int t=0; t<=SS; ++t)
        enc_step<<<256, 256, 0, stream>>>(t, zx0, WhhT0e, WihT1e, WhhT1e, b1e,
                                          h1buf, c1, h2buf, c2, enc_out);

    // enc_proj = enc_out @ att_Wh^T       (5120 x 256, K=256)
    gemm_nt<64,64,4,4><<<dim3(4,80), 256, 0, stream>>>(
        SS*BB, HH, HH, enc_out, HH, attWh, HH, encproj, HH, nullptr, nullptr);

    const float* encH1 = h1buf + 16384;   // h1 after step 79 (parity 1)
    const float* encH2 = h2buf;           // h2 after step 79 (parity 0)

    for (int t=0; t<TT; ++t){
        const float* h2prev = (t==0) ? encH2 : (h2all + (size_t)(t-1)*16384);
        dec_attn<<<64, 256, 0, stream>>>(h2prev, encproj, enc_out, aWsT, att_v,
                                         M3, attcb, cov, ctx);
        const float* h1in = (t==0) ? encH1 : (h1dec + ((t-1)&1)*16384);
        float* h1out = h1dec + (t&1)*16384;
        // layer0: z = embproj[t] + ctx@Wih0[:,256:]^T + h1@Whh0^T
        dec_lstm<<<128, 256, 0, stream>>>(ctx, h1in, dWih0T + 256*1024, dWhh0T,
                                          nullptr, embproj + (size_t)t*65536, c1, h1out);
        // layer1: z = h1@Wih1^T + h2@Whh1^T + (bih1+bhh1)
        dec_lstm<<<128, 256, 0, stream>>>(h1out, h2prev, dWih1T, dWhh1T,
                                          b1d, nullptr, c2, h2all + (size_t)t*16384);
    }

    ln_kernel<<<BB*TT, 256, 0, stream>>>(h2all, ln_g, ln_b, normed);

    // logits = normed @ W_out^T + b_out   (1280 x 32000, K=256) -> out[b][t][v]
    gemm_nt<64,128,4,8><<<dim3(VV/128, BB*TT/64), 256, 0, stream>>>(
        BB*TT, VV, HH, normed, HH, W_out, HH, out, VV, b_out, nullptr);
}

// Round 2
// 2295.388 us; speedup vs baseline: 1.8145x; 1.8145x over previous
//
#include <hip/hip_runtime.h>
#include <math.h>

// Problem constants
#define BB 64
#define SS 80
#define TT 20
#define FF 4096
#define HH 256
#define VV 32000

typedef __attribute__((ext_vector_type(8))) short bf16x8;
typedef __attribute__((ext_vector_type(4))) float f32x4;

__device__ __forceinline__ float fsig(float x){ return 1.f/(1.f+__expf(-x)); }
__device__ __forceinline__ float ftanh(float x){
    float xc = fminf(fmaxf(x,-15.f),15.f);
    float e = __expf(2.f*xc);
    return (e-1.f)/(e+1.f);
}
// fp32 -> bf16 (RNE), result in low 16 bits
__device__ __forceinline__ unsigned int f2b(float x){
    unsigned int u = __float_as_uint(x);
    return (u + 0x7fffu + ((u>>16)&1u)) >> 16;
}
__device__ __forceinline__ float blo(unsigned int u){ return __uint_as_float(u<<16); }
__device__ __forceinline__ float bhi(unsigned int u){ return __uint_as_float(u & 0xffff0000u); }

// ---------------------------------------------------------------------------
// prep: packed-bf16 recurrence weights, aWs transpose, M3, bias sums, gathers,
//       W_out -> bf16
// pk layout: pk[k*512 + j] = bf16(W[j][k]) | bf16(W[j+512][k])<<16,  j in [0,512)
// ---------------------------------------------------------------------------
__global__ __launch_bounds__(256) void prep_kernel(
    const float* __restrict__ eWhh0, const float* __restrict__ eWih1, const float* __restrict__ eWhh1,
    const float* __restrict__ dWih0, const float* __restrict__ dWhh0, const float* __restrict__ dWih1,
    const float* __restrict__ dWhh1, const float* __restrict__ attWs, const float* __restrict__ attWc,
    const float* __restrict__ cov_w, const float* __restrict__ cov_b,
    const float* __restrict__ e_bih0, const float* __restrict__ e_bhh0,
    const float* __restrict__ e_bih1, const float* __restrict__ e_bhh1,
    const float* __restrict__ d_bih0, const float* __restrict__ d_bhh0,
    const float* __restrict__ d_bih1, const float* __restrict__ d_bhh1,
    const int*   __restrict__ captions, const float* __restrict__ W_out,
    unsigned int* pkWhh0e, unsigned int* pkWih1e, unsigned int* pkWhh1e, unsigned int* pkWx0d,
    unsigned int* pkWhh0d, unsigned int* pkWih1d, unsigned int* pkWhh1d,
    float* aWsT, float* M3, float* attcb,
    float* b0e, float* b1e, float* b0d, float* b1d, int* g2, int* g3,
    unsigned short* Wob)
{
    int blk = blockIdx.x, tid = threadIdx.x;
    if (blk < 896){
        int mat = blk >> 7, tl = blk & 127;
        const float* src; int stride, coff; unsigned int* dst;
        switch(mat){
            case 0: src=eWhh0; stride=256; coff=0;   dst=pkWhh0e; break;
            case 1: src=eWih1; stride=256; coff=0;   dst=pkWih1e; break;
            case 2: src=eWhh1; stride=256; coff=0;   dst=pkWhh1e; break;
            case 3: src=dWih0; stride=512; coff=256; dst=pkWx0d;  break;  // ctx columns
            case 4: src=dWhh0; stride=256; coff=0;   dst=pkWhh0d; break;
            case 5: src=dWih1; stride=256; coff=0;   dst=pkWih1d; break;
            default:src=dWhh1; stride=256; coff=0;   dst=pkWhh1d; break;
        }
        int jt = tl >> 3, kt = tl & 7;       // 16 j-tiles x 8 k-tiles
        int j0 = jt*32, k0 = kt*32;
        __shared__ float t1[32][33], t2[32][33];
        int r = tid >> 5, c = tid & 31;
        #pragma unroll
        for (int i=0;i<4;i++){
            int row = r + i*8;
            t1[row][c] = src[(size_t)(j0+row)*stride     + coff + k0 + c];
            t2[row][c] = src[(size_t)(j0+512+row)*stride + coff + k0 + c];
        }
        __syncthreads();
        #pragma unroll
        for (int i=0;i<4;i++){
            int row = r + i*8;               // k index within tile
            dst[(size_t)(k0+row)*512 + j0 + c] = f2b(t1[c][row]) | (f2b(t2[c][row])<<16);
        }
        return;
    }
    if (blk < 960){
        // transpose attWs (256x256) -> aWsT
        int tl = blk - 896; int rt = tl/8, ct = tl%8;
        __shared__ float tile[32][33];
        int ty = tid>>5, tx = tid&31;
        #pragma unroll
        for (int i=0;i<4;i++){ int r=ty+i*8; tile[r][tx] = attWs[(size_t)(rt*32+r)*256 + ct*32+tx]; }
        __syncthreads();
        #pragma unroll
        for (int i=0;i<4;i++){ int r=ty+i*8; aWsT[(size_t)(ct*32+r)*256 + rt*32+tx] = tile[tx][r]; }
        return;
    }
    if (blk == 960){
        float m0=0.f,m1=0.f,m2=0.f,cb=0.f;
        for (int c=0;c<64;c++){
            float w = attWc[tid*64+c];
            m0 += w*cov_w[c*3+0]; m1 += w*cov_w[c*3+1]; m2 += w*cov_w[c*3+2];
            cb += w*cov_b[c];
        }
        M3[tid*3+0]=m0; M3[tid*3+1]=m1; M3[tid*3+2]=m2; attcb[tid]=cb;
        return;
    }
    if (blk == 961){
        for (int i=tid;i<1024;i+=256){
            b0e[i]=e_bih0[i]+e_bhh0[i]; b1e[i]=e_bih1[i]+e_bhh1[i];
            b0d[i]=d_bih0[i]+d_bhh0[i]; b1d[i]=d_bih1[i]+d_bhh1[i];
        }
        return;
    }
    if (blk == 962){
        for (int m=tid;m<SS*BB;m+=256) g2[m] = (m&63)*SS + (m>>6);
        return;
    }
    if (blk == 963){
        for (int m=tid;m<TT*BB;m+=256) g3[m] = captions[(m&63)*TT + (m>>6)];
        return;
    }
    // W_out -> bf16 (8.192M elements, 4000 blocks x 2048 els)
    {
        size_t idx = (size_t)(blk-964)*2048 + tid*8;
        float4 a  = *reinterpret_cast<const float4*>(W_out+idx);
        float4 b4 = *reinterpret_cast<const float4*>(W_out+idx+4);
        uint4 o;
        o.x = f2b(a.x)  | (f2b(a.y)<<16);
        o.y = f2b(a.z)  | (f2b(a.w)<<16);
        o.z = f2b(b4.x) | (f2b(b4.y)<<16);
        o.w = f2b(b4.z) | (f2b(b4.w)<<16);
        *reinterpret_cast<uint4*>(Wob+idx) = o;
    }
}

// ---------------------------------------------------------------------------
// Generic tiled fp32 GEMM: C = A[M,K] @ B[N,K]^T (+bias), A-row gather, split-K
// ---------------------------------------------------------------------------
template<int BM,int BN,int TM,int TN>
__global__ __launch_bounds__(256) void gemm_nt(int M,int N,int K,
    const float* __restrict__ A, int lda,
    const float* __restrict__ B, int ldb,
    float* __restrict__ C, int ldc,
    const float* __restrict__ bias,
    const int* __restrict__ gatherA,
    int Ksl, size_t Cslice)
{
    constexpr int BK=16;
    constexpr int TX=BN/TN, TY=BM/TM;
    static_assert(TX*TY==256, "256 threads");
    __shared__ float As[BK][BM+4];
    __shared__ float Bs[BK][BN+4];
    int tid = threadIdx.x;
    int tx = tid%TX, ty = tid/TX;
    int m0 = blockIdx.y*BM, n0 = blockIdx.x*BN;
    int kz = blockIdx.z;
    int kstart = kz*Ksl, kend = min(K, kstart+Ksl);
    C += (size_t)kz * Cslice;
    const float* bz = (kz==0) ? bias : nullptr;
    float acc[TM][TN] = {};
    int lr = tid>>2, lk = (tid&3)*4;
    for (int k0=kstart;k0<kend;k0+=BK){
        #pragma unroll
        for (int r=lr;r<BM;r+=64){
            int arow = gatherA ? gatherA[m0+r] : (m0+r);
            float4 v = *reinterpret_cast<const float4*>(A + (size_t)arow*lda + k0 + lk);
            As[lk+0][r]=v.x; As[lk+1][r]=v.y; As[lk+2][r]=v.z; As[lk+3][r]=v.w;
        }
        #pragma unroll
        for (int r=lr;r<BN;r+=64){
            float4 v = *reinterpret_cast<const float4*>(B + (size_t)(n0+r)*ldb + k0 + lk);
            Bs[lk+0][r]=v.x; Bs[lk+1][r]=v.y; Bs[lk+2][r]=v.z; Bs[lk+3][r]=v.w;
        }
        __syncthreads();
        #pragma unroll
        for (int k=0;k<BK;k++){
            float a[TM], bv[TN];
            #pragma unroll
            for (int i=0;i<TM;i++) a[i]=As[k][ty*TM+i];
            #pragma unroll
            for (int j=0;j<TN;j++) bv[j]=Bs[k][tx*TN+j];
            #pragma unroll
            for (int i=0;i<TM;i++)
                #pragma unroll
                for (int j=0;j<TN;j++) acc[i][j] += a[i]*bv[j];
        }
        __syncthreads();
    }
    #pragma unroll
    for (int i=0;i<TM;i++){
        size_t m = m0 + ty*TM + i;
        #pragma unroll
        for (int j=0;j<TN;j++){
            int n = n0 + tx*TN + j;
            C[m*ldc + n] = acc[i][j] + (bz ? bz[n] : 0.f);
        }
    }
}

// sum 4 split-K partials -> vp
__global__ __launch_bounds__(256) void vp_reduce(const float* __restrict__ part,
                                                 float* __restrict__ vp)
{
    size_t i = (size_t)blockIdx.x*256 + threadIdx.x;   // float4 index
    const float4* p = reinterpret_cast<const float4*>(part);
    float4 a = p[i], b = p[i+327680], c = p[i+655360], d = p[i+983040];
    a.x += b.x+c.x+d.x; a.y += b.y+c.y+d.y; a.z += b.z+c.z+d.z; a.w += b.w+c.w+d.w;
    reinterpret_cast<float4*>(vp)[i] = a;
}

// ---------------------------------------------------------------------------
// LSTM z + pointwise, packed-bf16 weights. Block = 4 batches x 32 h-outputs.
// Wpk[k*512+j] packs gate-pair columns (j, j+512).
// ---------------------------------------------------------------------------
__device__ __forceinline__ void lstm_body(int lb, int tid,
    const float* __restrict__ xrow, const float* __restrict__ hrow,
    const unsigned int* __restrict__ WxPk, const unsigned int* __restrict__ WhPk,
    const float* __restrict__ bias, const float* __restrict__ baserows,
    float* __restrict__ cbuf, float* __restrict__ hout,
    float* __restrict__ extra, int extra_stride)
{
    int bc = lb>>3, hc = lb&7, b0 = bc*4;
    __shared__ float xs[4][256];
    __shared__ float hs[4][256];
    __shared__ float zs[4][4][32];
    for (int i=tid;i<1024;i+=256){
        int bb2=i>>8, k=i&255;
        hs[bb2][k] = hrow[(b0+bb2)*256 + k];
        if (xrow) xs[bb2][k] = xrow[(b0+bb2)*256 + k];
    }
    __syncthreads();
    int b_l = tid>>6, inner = tid&63, gate = inner>>5, h_l = inner&31;
    int b = b0 + b_l;
    int j0 = gate*256 + hc*32 + h_l;   // in [0,512); pair column is j0+512
    float acc0 = 0.f, acc1 = 0.f;
    if (bias)     { acc0 += bias[j0];                       acc1 += bias[j0+512]; }
    if (baserows) { acc0 += baserows[(size_t)b*1024 + j0];  acc1 += baserows[(size_t)b*1024 + j0 + 512]; }
    const unsigned int* wh = WhPk + j0;
    if (WxPk){
        const unsigned int* wx = WxPk + j0;
        #pragma unroll 8
        for (int k=0;k<256;k++){
            float xv = xs[b_l][k], hv = hs[b_l][k];
            unsigned int uw = wx[(size_t)k*512], uh = wh[(size_t)k*512];
            acc0 += xv*blo(uw) + hv*blo(uh);
            acc1 += xv*bhi(uw) + hv*bhi(uh);
        }
    } else {
        #pragma unroll 8
        for (int k=0;k<256;k++){
            float hv = hs[b_l][k];
            unsigned int uh = wh[(size_t)k*512];
            acc0 += hv*blo(uh);
            acc1 += hv*bhi(uh);
        }
    }
    zs[b_l][gate  ][h_l] = acc0;
    zs[b_l][gate+2][h_l] = acc1;
    __syncthreads();
    if (tid < 128){
        int pb = tid>>5, ph = tid&31;
        int bb2 = b0+pb, h = hc*32+ph, idx = bb2*256 + h;
        float i_ = zs[pb][0][ph], f_ = zs[pb][1][ph], g_ = zs[pb][2][ph], o_ = zs[pb][3][ph];
        float cn = fsig(f_)*cbuf[idx] + fsig(i_)*ftanh(g_);
        cbuf[idx] = cn;
        float hn = fsig(o_)*ftanh(cn);
        hout[idx] = hn;
        if (extra) extra[(size_t)bb2*extra_stride + h] = hn;
    }
}

// Encoder: pipelined — blocks 0..127 do layer0 step t, blocks 128..255 layer1 step t-1
__global__ __launch_bounds__(256) void enc_step(int t,
    const float* __restrict__ zx0, const unsigned int* __restrict__ pkWhh0e,
    const unsigned int* __restrict__ pkWih1e, const unsigned int* __restrict__ pkWhh1e,
    const float* __restrict__ b1e,
    float* h1buf, float* c1, float* h2buf, float* c2, float* enc_out)
{
    int blk = blockIdx.x, tid = threadIdx.x;
    if (blk < 128){
        if (t >= SS) return;
        const float* h1prev = h1buf + ((t+1)&1)*16384;
        float* h1cur        = h1buf + (t&1)*16384;
        lstm_body(blk, tid, nullptr, h1prev, nullptr, pkWhh0e, nullptr,
                  zx0 + (size_t)t*65536, c1, h1cur, nullptr, 0);
    } else {
        if (t < 1) return;
        int u = t-1;
        const float* h1row  = h1buf + (u&1)*16384;
        const float* h2prev = h2buf + (u&1)*16384;
        float* h2next       = h2buf + ((u+1)&1)*16384;
        lstm_body(blk-128, tid, h1row, h2prev, pkWih1e, pkWhh1e, b1e, nullptr,
                  c2, h2next, enc_out + (size_t)u*256, SS*256);
    }
}

__global__ __launch_bounds__(256) void dec_lstm(
    const float* __restrict__ xrow, const float* __restrict__ hrow,
    const unsigned int* __restrict__ WxPk, const unsigned int* __restrict__ WhPk,
    const float* __restrict__ bias, const float* __restrict__ baserows,
    float* cbuf, float* hout)
{
    lstm_body(blockIdx.x, threadIdx.x, xrow, hrow, WxPk, WhPk, bias, baserows,
              cbuf, hout, nullptr, 0);
}

// ---------------------------------------------------------------------------
// Decoder attention (one block per batch row) — unchanged fp32
// ---------------------------------------------------------------------------
__global__ __launch_bounds__(256) void dec_attn(
    const float* __restrict__ h2prev, const float* __restrict__ encp,
    const float* __restrict__ enco, const float* __restrict__ WsT,
    const float* __restrict__ att_v, const float* __restrict__ M3,
    const float* __restrict__ attcb, float* __restrict__ cov,
    float* __restrict__ ctx)
{
    int b = blockIdx.x, tid = threadIdx.x;
    __shared__ float h2s[256], dps[256];
    __shared__ float covs[82], scs[80], attns[80];
    h2s[tid] = h2prev[b*256 + tid];
    if (tid < 80) covs[tid+1] = cov[b*80 + tid];
    if (tid == 80) covs[0] = 0.f;
    if (tid == 81) covs[81] = 0.f;
    __syncthreads();
    {
        float acc = attcb[tid];
        for (int k=0;k<256;k++) acc += h2s[k]*WsT[k*256 + tid];
        dps[tid] = acc;
    }
    __syncthreads();
    int wave = tid>>6, lane = tid&63;
    float va[4], dp4[4], m30[4], m31[4], m32[4];
    #pragma unroll
    for (int i=0;i<4;i++){
        int h = lane + i*64;
        va[i]=att_v[h]; dp4[i]=dps[h];
        m30[i]=M3[h*3+0]; m31[i]=M3[h*3+1]; m32[i]=M3[h*3+2];
    }
    for (int s = wave*20; s < wave*20 + 20; s++){
        float c0 = covs[s], c1v = covs[s+1], c2v = covs[s+2];
        float p = 0.f;
        #pragma unroll
        for (int i=0;i<4;i++){
            int h = lane + i*64;
            float e = encp[((size_t)b*80 + s)*256 + h] + dp4[i] + m30[i]*c0 + m31[i]*c1v + m32[i]*c2v;
            p += va[i]*ftanh(e);
        }
        #pragma unroll
        for (int off=32;off;off>>=1) p += __shfl_down(p, off);
        if (lane == 0) scs[s] = p;
    }
    __syncthreads();
    if (tid < 64){
        float a = scs[tid];
        float bsc = (tid < 16) ? scs[tid+64] : -3.4e38f;
        float mx = fmaxf(a, bsc);
        #pragma unroll
        for (int off=32;off;off>>=1) mx = fmaxf(mx, __shfl_xor(mx, off));
        float ea = __expf(a - mx);
        float eb = (tid < 16) ? __expf(bsc - mx) : 0.f;
        float sum = ea + eb;
        #pragma unroll
        for (int off=32;off;off>>=1) sum += __shfl_xor(sum, off);
        float inv = 1.f/sum;
        attns[tid] = ea*inv;
        if (tid < 16) attns[tid+64] = eb*inv;
    }
    __syncthreads();
    if (tid < 80) cov[b*80 + tid] = covs[tid+1] + attns[tid];
    float cacc = 0.f;
    for (int s=0;s<80;s++) cacc += attns[s]*enco[((size_t)b*80 + s)*256 + tid];
    ctx[b*256 + tid] = cacc;
}

// ---------------------------------------------------------------------------
// LayerNorm -> bf16 rows for the logits MFMA
// ---------------------------------------------------------------------------
__global__ __launch_bounds__(256) void ln_kernel(
    const float* __restrict__ h2all, const float* __restrict__ g,
    const float* __restrict__ be, unsigned short* __restrict__ normedb)
{
    int row = blockIdx.x;           // b*20 + t
    int b = row/TT, t = row%TT;
    int tid = threadIdx.x;
    __shared__ float red[4];
    float x = h2all[((size_t)t*64 + b)*256 + tid];
    float s = x;
    #pragma unroll
    for (int off=32;off;off>>=1) s += __shfl_down(s, off);
    if ((tid&63) == 0) red[tid>>6] = s;
    __syncthreads();
    float mean = (red[0]+red[1]+red[2]+red[3]) * (1.f/256.f);
    __syncthreads();
    float d = x - mean;
    float sq = d*d;
    #pragma unroll
    for (int off=32;off;off>>=1) sq += __shfl_down(sq, off);
    if ((tid&63) == 0) red[tid>>6] = sq;
    __syncthreads();
    float var = (red[0]+red[1]+red[2]+red[3]) * (1.f/256.f);
    float val = d*rsqrtf(var + 1e-5f)*g[tid] + be[tid];
    normedb[(size_t)row*256 + tid] = (unsigned short)f2b(val);
}

// ---------------------------------------------------------------------------
// Logits: bf16 MFMA, LDS-free (fragments loaded straight from global rows)
// C = A[1280,256] @ W[32000,256]^T + b   -> out fp32
// Block: 64(M) x 64(N); wave w owns rows m0+w*16, cols n0..n0+63
// ---------------------------------------------------------------------------
__global__ __launch_bounds__(256) void logits_mfma(
    const short* __restrict__ A, const short* __restrict__ Bw,
    const float* __restrict__ bias, float* __restrict__ out)
{
    int w = threadIdx.x >> 6, lane = threadIdx.x & 63;
    int m0 = blockIdx.y*64 + w*16, n0 = blockIdx.x*64;
    int row = lane & 15, kg = lane >> 4;
    const short* arow = A + (size_t)(m0 + row)*256 + kg*8;
    f32x4 acc[4] = {};
    for (int kk=0; kk<8; ++kk){
        bf16x8 a = *reinterpret_cast<const bf16x8*>(arow + kk*32);
        #pragma unroll
        for (int f=0; f<4; ++f){
            bf16x8 b = *reinterpret_cast<const bf16x8*>(
                Bw + (size_t)(n0 + f*16 + row)*256 + kk*32 + kg*8);
            acc[f] = __builtin_amdgcn_mfma_f32_16x16x32_bf16(a, b, acc[f], 0, 0, 0);
        }
    }
    #pragma unroll
    for (int f=0; f<4; ++f){
        int n = n0 + f*16 + row;           // col = lane&15
        float bv = bias[n];
        #pragma unroll
        for (int r=0; r<4; ++r){
            int m = m0 + kg*4 + r;         // row = (lane>>4)*4 + reg
            out[(size_t)m*VV + n] = acc[f][r] + bv;
        }
    }
}

// ---------------------------------------------------------------------------
extern "C" void kernel_launch(void* const* d_in, const int* in_sizes, int n_in,
                              void* d_out, int out_size, void* d_ws, size_t ws_size,
                              hipStream_t stream)
{
    const float* video  = (const float*)d_in[0];
    const int*   caps   = (const int*)  d_in[1];
    const float* W_vp   = (const float*)d_in[2];
    const float* b_vp   = (const float*)d_in[3];
    const float* eWih0  = (const float*)d_in[4];
    const float* eWhh0  = (const float*)d_in[5];
    const float* e_bih0 = (const float*)d_in[6];
    const float* e_bhh0 = (const float*)d_in[7];
    const float* eWih1  = (const float*)d_in[8];
    const float* eWhh1  = (const float*)d_in[9];
    const float* e_bih1 = (const float*)d_in[10];
    const float* e_bhh1 = (const float*)d_in[11];
    const float* emb    = (const float*)d_in[12];
    const float* dWih0  = (const float*)d_in[13];
    const float* dWhh0  = (const float*)d_in[14];
    const float* d_bih0 = (const float*)d_in[15];
    const float* d_bhh0 = (const float*)d_in[16];
    const float* dWih1  = (const float*)d_in[17];
    const float* dWhh1  = (const float*)d_in[18];
    const float* d_bih1 = (const float*)d_in[19];
    const float* d_bhh1 = (const float*)d_in[20];
    const float* attWh  = (const float*)d_in[21];
    const float* attWs  = (const float*)d_in[22];
    const float* att_v  = (const float*)d_in[23];
    const float* attWc  = (const float*)d_in[24];
    const float* cov_w  = (const float*)d_in[25];
    const float* cov_b  = (const float*)d_in[26];
    const float* ln_g   = (const float*)d_in[27];
    const float* ln_b   = (const float*)d_in[28];
    const float* W_out  = (const float*)d_in[29];
    const float* b_out  = (const float*)d_in[30];
    float* out = (float*)d_out;

    float* W = (float*)d_ws;
    size_t o = 0;
    auto alloc = [&](size_t n){ size_t r = o; o += ((n + 63)/64)*64; return r; };

    // zero-initialized state region (contiguous, memset below)
    float* h1buf = W + alloc(2*64*256);
    float* h2buf = W + alloc(2*64*256);
    float* c1    = W + alloc(64*256);
    float* c2    = W + alloc(64*256);
    float* cov   = W + alloc(64*80);
    size_t state_bytes = o * sizeof(float);

    float* h1dec   = W + alloc(2*64*256);
    float* vp      = W + alloc((size_t)SS*BB*HH);       // [b][s][h] fp32
    float* zx0     = W + alloc((size_t)SS*BB*1024);     // [t][b][1024]; aliases vp_part
    float* vp_part = zx0;                               // 4 x (5120*256) split-K partials
    float* embproj = W + alloc((size_t)TT*BB*1024);     // [t][b][1024]
    float* enc_out = W + alloc((size_t)BB*SS*HH);       // [b][s][h]
    float* encproj = W + alloc((size_t)BB*SS*HH);       // [b][s][h]
    float* h2all   = W + alloc((size_t)TT*BB*HH);       // [t][b][h]
    float* ctx     = W + alloc((size_t)BB*HH);
    unsigned short* normedb = (unsigned short*)(W + alloc((size_t)BB*TT*HH/2));
    unsigned int* pkWhh0e = (unsigned int*)(W + alloc(256*512));
    unsigned int* pkWih1e = (unsigned int*)(W + alloc(256*512));
    unsigned int* pkWhh1e = (unsigned int*)(W + alloc(256*512));
    unsigned int* pkWx0d  = (unsigned int*)(W + alloc(256*512));
    unsigned int* pkWhh0d = (unsigned int*)(W + alloc(256*512));
    unsigned int* pkWih1d = (unsigned int*)(W + alloc(256*512));
    unsigned int* pkWhh1d = (unsigned int*)(W + alloc(256*512));
    float* aWsT    = W + alloc(256*256);
    float* M3      = W + alloc(256*3);
    float* attcb   = W + alloc(256);
    float* b0e     = W + alloc(1024);
    float* b1e     = W + alloc(1024);
    float* b0d     = W + alloc(1024);
    float* b1d     = W + alloc(1024);
    int*   g2      = (int*)(W + alloc(SS*BB));
    int*   g3      = (int*)(W + alloc(TT*BB));
    unsigned short* Wob = (unsigned short*)(W + alloc((size_t)VV*HH/2));
    (void)ws_size; (void)n_in; (void)in_sizes; (void)out_size;

    hipMemsetAsync(W, 0, state_bytes, stream);

    prep_kernel<<<4964, 256, 0, stream>>>(
        eWhh0, eWih1, eWhh1, dWih0, dWhh0, dWih1, dWhh1, attWs, attWc,
        cov_w, cov_b, e_bih0, e_bhh0, e_bih1, e_bhh1, d_bih0, d_bhh0, d_bih1, d_bhh1,
        caps, W_out,
        pkWhh0e, pkWih1e, pkWhh1e, pkWx0d, pkWhh0d, pkWih1d, pkWhh1d,
        aWsT, M3, attcb, b0e, b1e, b0d, b1d, g2, g3, Wob);

    // vp = video @ W_vp^T + b_vp   (5120x256, K=4096) — split-K x4 partials
    gemm_nt<64,64,4,4><<<dim3(4,80,4), 256, 0, stream>>>(
        SS*BB, HH, FF, video, FF, W_vp, FF, vp_part, HH, b_vp, nullptr,
        1024, (size_t)SS*BB*HH);
    vp_reduce<<<1280, 256, 0, stream>>>(vp_part, vp);

    // zx0[t][b] = vp[b][t] @ eWih0^T + (bih0+bhh0)   (5120x1024, K=256)
    gemm_nt<64,64,4,4><<<dim3(16,80), 256, 0, stream>>>(
        SS*BB, 1024, HH, vp, HH, eWih0, HH, zx0, 1024, b0e, g2, HH, 0);

    // embproj[t][b] = emb[tok] @ dWih0[:, :256]^T + (bih0+bhh0)   (1280x1024, K=256)
    gemm_nt<64,64,4,4><<<dim3(16,20), 256, 0, stream>>>(
        TT*BB, 1024, HH, emb, HH, dWih0, 512, embproj, 1024, b0d, g3, HH, 0);

    // encoder scan (pipelined: layer0(t) || layer1(t-1))
    for (int t=0; t<=SS; ++t)
        enc_step<<<256, 256, 0, stream>>>(t, zx0, pkWhh0e, pkWih1e, pkWhh1e, b1e,
                                          h1buf, c1, h2buf, c2, enc_out);

    // enc_proj = enc_out @ att_Wh^T   (5120x256, K=256)
    gemm_nt<64,64,4,4><<<dim3(4,80), 256, 0, stream>>>(
        SS*BB, HH, HH, enc_out, HH, attWh, HH, encproj, HH, nullptr, nullptr, HH, 0);

    const float* encH1 = h1buf + 16384;   // h1 after step 79 (parity 1)
    const float* encH2 = h2buf;           // h2 after step 79 (parity 0)

    for (int t=0; t<TT; ++t){
        const float* h2prev = (t==0) ? encH2 : (h2all + (size_t)(t-1)*16384);
        dec_attn<<<64, 256, 0, stream>>>(h2prev, encproj, enc_out, aWsT, att_v,
                                         M3, attcb, cov, ctx);
        const float* h1in = (t==0) ? encH1 : (h1dec + ((t-1)&1)*16384);
        float* h1out = h1dec + (t&1)*16384;
        dec_lstm<<<128, 256, 0, stream>>>(ctx, h1in, pkWx0d, pkWhh0d,
                                          nullptr, embproj + (size_t)t*65536, c1, h1out);
        dec_lstm<<<128, 256, 0, stream>>>(h1out, h2prev, pkWih1d, pkWhh1d,
                                          b1d, nullptr, c2, h2all + (size_t)t*16384);
    }

    ln_kernel<<<BB*TT, 256, 0, stream>>>(h2all, ln_g, ln_b, normedb);

    // logits = normed @ W_out^T + b_out   (1280 x 32000, K=256)
    logits_mfma<<<dim3(VV/64, BB*TT/64), 256, 0, stream>>>(
        (const short*)normedb, (const short*)Wob, b_out, out);
}